// Round 5
// baseline (235.452 us; speedup 1.0000x reference)
//
#include <hip/hip_runtime.h>
#include <hip/hip_bf16.h>

// C[32768,2304] = A[32768,768] * W^T + b ; outputs q,k,v [32768,768] fp32 each.
#define M_TOT 32768
#define K_TOT 768
#define N_TOT 2304
#define H     768
#define BM 256
#define BN 256
#define BK 32
#define NBN 9                    // N_TOT/BN
#define NBM 128                  // M_TOT/BM
#define NBLK (NBM*NBN)           // 1152, %8==0 -> XCD swizzle bijective
#define NKT  (K_TOT/BK)          // 24
#define OUT_PER 25165824         // M_TOT*H

typedef __attribute__((ext_vector_type(8))) short bf16x8;
typedef __attribute__((ext_vector_type(8))) unsigned short u16x8;
typedef __attribute__((ext_vector_type(4))) float f32x4;

__device__ __forceinline__ void gld_lds16(const void* g, void* l) {
    __builtin_amdgcn_global_load_lds(
        (const __attribute__((address_space(1))) unsigned int*)g,
        (__attribute__((address_space(3))) unsigned int*)l,
        16, 0, 0);
}

__device__ __forceinline__ unsigned short f2bf_rne(float f) {
    unsigned u = __builtin_bit_cast(unsigned, f);
    unsigned r = (u + 0x7FFFu + ((u >> 16) & 1u)) >> 16;
    return (unsigned short)r;
}

// ---------------------------------------------------------------------------
// Pass 1 (verbatim R3, measured ~25us): fp32 -> bf16 convert + pack into
// tiled layout pk[tile][kb8][row128][8], tile = 128 rows x 64 k.
// ---------------------------------------------------------------------------
#define A_TILES 3072             // 256 m-granules x 12 k-granules
#define W_TILES 216              // 18 row-granules x 12 k-granules
#define LDSW 68

__global__ void convert_pack(const float* __restrict__ A,
                             const float* __restrict__ wq, const float* __restrict__ wk,
                             const float* __restrict__ wv,
                             const float* __restrict__ bq, const float* __restrict__ bk,
                             const float* __restrict__ bv,
                             unsigned short* __restrict__ A_pk,
                             unsigned short* __restrict__ W_pk,
                             float* __restrict__ biasb) {
    __shared__ float lds_f[128 * LDSW];

    const int tid = threadIdx.x;
    const int t   = blockIdx.x;

    int gt = t * 256 + tid;
    if (gt < 2304) {
        biasb[gt] = (gt < 768) ? bq[gt] : (gt < 1536) ? bk[gt - 768] : bv[gt - 1536];
    }

    const float* src;
    unsigned short* dst;
    if (t < A_TILES) {
        const int mt = t / 12, kt = t - mt * 12;
        src = A + (size_t)mt * 128 * K_TOT + kt * 64;
        dst = A_pk + (size_t)t * 8192;
    } else {
        const int t2 = t - A_TILES;
        const int nt = t2 / 12, kt = t2 - nt * 12;
        const int which = nt / 6;
        const int row0  = (nt - which * 6) * 128;
        const float* w = (which == 0) ? wq : (which == 1) ? wk : wv;
        src = w + (size_t)row0 * K_TOT + kt * 64;
        dst = W_pk + (size_t)t2 * 8192;
    }

    #pragma unroll
    for (int j = 0; j < 8; ++j) {
        int f = j * 256 + tid;
        int row = f >> 4, c4 = f & 15;
        float4 v = *reinterpret_cast<const float4*>(src + (size_t)row * K_TOT + c4 * 4);
        *reinterpret_cast<float4*>(&lds_f[row * LDSW + c4 * 4]) = v;
    }
    __syncthreads();

    #pragma unroll
    for (int j = 0; j < 4; ++j) {
        int c = j * 256 + tid;
        int kb = c >> 7, row = c & 127;
        const float* p = &lds_f[row * LDSW + kb * 8];
        u16x8 o;
        #pragma unroll
        for (int e = 0; e < 8; ++e) o[e] = f2bf_rne(p[e]);
        *reinterpret_cast<u16x8*>(dst + (size_t)c * 8) = o;
    }
}

// ---------------------------------------------------------------------------
// Pass 2: 256x256 (BK=32) bf16 MFMA GEMM, m201-ratio phases:
//   512 thr = 8 waves (2M x 4N), wave tile 128x64, acc[8][4] f32x4.
//   4-slot LDS ring (128 KiB), 3-tile prefetch lead -> gate vmcnt(8) +
//   s_barrier (collective), never 0 until last 2 tiles.
//   Per K-tile: 2 phases {8|4 ds_read_b128 | 2 gld_lds | bar | lgkm0+sb0 |
//   setprio(1) 16 MFMA setprio(0) | bar}.
//   Packed slot [kb4][row256][8]: ds_read_b128 conflict-free (R3/R4: 0 conf).
// ---------------------------------------------------------------------------
__global__ __launch_bounds__(512, 1) void qkv_gemm(
        const unsigned short* __restrict__ A_pk,
        const unsigned short* __restrict__ W_pk,
        const float* __restrict__ bias,
        float* __restrict__ out) {

    __shared__ __align__(16) unsigned short sA[4][8192];   // 64 KiB
    __shared__ __align__(16) unsigned short sB[4][8192];   // 64 KiB

    const int tid  = threadIdx.x;
    const int lane = tid & 63;
    const int wid  = tid >> 6;     // 0..7
    const int wm   = wid >> 2;     // 0..1 : rows wm*128..+127
    const int wn   = wid & 3;      // 0..3 : cols wn*64..+63

    int bid = (int)blockIdx.x;
    bid = (bid & 7) * (NBLK / 8) + (bid >> 3);   // XCD-aware (bijective)
    const int bm = bid / NBN;
    const int bn = bid - bm * NBN;
    const int m0 = bm * BM;
    const int n0 = bn * BN;

    // ---- staging: per tile 4 loads/thread, issue order A1,A2,B1,B2.
    // chunk c=tid -> slot elem c*8 ; chunk c=512+tid -> +4096 elems.
    // global src (bytes): granule (2*bm + rowbit)*196608 + kb4*2048 +
    //   (tid&127)*16 + t*8192 ; chunk2 = +4096.
    const char* aBase = (const char*)A_pk
        + (size_t)(2 * bm + ((tid >> 7) & 1)) * 196608
        + (tid >> 8) * 2048 + (tid & 127) * 16;
    const char* bBase = (const char*)W_pk
        + (size_t)(2 * bn + ((tid >> 7) & 1)) * 196608
        + (tid >> 8) * 2048 + (tid & 127) * 16;

    f32x4 acc[8][4];
    #pragma unroll
    for (int i = 0; i < 8; ++i)
        #pragma unroll
        for (int j = 0; j < 4; ++j)
            acc[i][j] = (f32x4){0.f, 0.f, 0.f, 0.f};

    auto stageA = [&](int t) {
        const int s = t & 3;
        gld_lds16(aBase + (size_t)t * 8192,        &sA[s][tid * 8]);
        gld_lds16(aBase + (size_t)t * 8192 + 4096, &sA[s][4096 + tid * 8]);
    };
    auto stageB = [&](int t) {
        const int s = t & 3;
        gld_lds16(bBase + (size_t)t * 8192,        &sB[s][tid * 8]);
        gld_lds16(bBase + (size_t)t * 8192 + 4096, &sB[s][4096 + tid * 8]);
    };

    // prologue: stage tiles 0,1,2 (12 loads; per-tile order A,A,B,B)
    #pragma unroll
    for (int t = 0; t < 3; ++t) { stageA(t); stageB(t); }

    // fragment read byte-offsets in slot [kb4][row][8]:
    const int aB = ((lane >> 4) << 12) + (wm * 128 + (lane & 15)) * 16;
    const int bB = ((lane >> 4) << 12) + (wn * 64  + (lane & 15)) * 16;

    for (int t = 0; t < NKT; ++t) {
        const int s = t & 3;

        // ---- gate: own tile-t loads landed (vmcnt) then collective (barrier)
        if (t < 22)      { asm volatile("s_waitcnt vmcnt(8)" ::: "memory"); }
        else if (t == 22){ asm volatile("s_waitcnt vmcnt(4)" ::: "memory"); }
        else             { asm volatile("s_waitcnt vmcnt(0)" ::: "memory"); }
        __builtin_amdgcn_s_barrier();

        const char* pA = (const char*)&sA[s][0];
        const char* pB = (const char*)&sB[s][0];

        bf16x8 af[4], bf[4];

        // ================= phase 0: rows wm*128..+63, all 4 n-frags =======
        #pragma unroll
        for (int mi = 0; mi < 4; ++mi)
            af[mi] = *(const bf16x8*)(pA + aB + mi * 256);
        #pragma unroll
        for (int nj = 0; nj < 4; ++nj)
            bf[nj] = *(const bf16x8*)(pB + bB + nj * 256);
        if (t < 21) stageA(t + 3);
        __builtin_amdgcn_s_barrier();
        asm volatile("s_waitcnt lgkmcnt(0)" ::: "memory");
        __builtin_amdgcn_sched_barrier(0);
        __builtin_amdgcn_s_setprio(1);
        #pragma unroll
        for (int mi = 0; mi < 4; ++mi)
            #pragma unroll
            for (int nj = 0; nj < 4; ++nj)
                acc[mi][nj] = __builtin_amdgcn_mfma_f32_16x16x32_bf16(
                    bf[nj], af[mi], acc[mi][nj], 0, 0, 0);
        __builtin_amdgcn_s_setprio(0);
        __builtin_amdgcn_s_barrier();

        // ================= phase 1: rows wm*128+64..+127, reuse bf ========
        #pragma unroll
        for (int mi = 0; mi < 4; ++mi)
            af[mi] = *(const bf16x8*)(pA + aB + 1024 + mi * 256);
        if (t < 21) stageB(t + 3);
        __builtin_amdgcn_s_barrier();
        asm volatile("s_waitcnt lgkmcnt(0)" ::: "memory");
        __builtin_amdgcn_sched_barrier(0);
        __builtin_amdgcn_s_setprio(1);
        #pragma unroll
        for (int mi = 0; mi < 4; ++mi)
            #pragma unroll
            for (int nj = 0; nj < 4; ++nj)
                acc[4 + mi][nj] = __builtin_amdgcn_mfma_f32_16x16x32_bf16(
                    bf[nj], af[mi], acc[4 + mi][nj], 0, 0, 0);
        __builtin_amdgcn_s_setprio(0);
        // (next gate barrier closes this phase)
    }

    // ---- epilogue: operand-swapped layout -> lane holds 4 consecutive n
    const int which = n0 / H;
    const int c0    = n0 - which * H;
    float* outB = out + (size_t)which * OUT_PER;

    #pragma unroll
    for (int j = 0; j < 4; ++j) {
        const int ncol = wn * 64 + j * 16 + ((lane >> 4) << 2);
        const float4 bv4 = *reinterpret_cast<const float4*>(&bias[n0 + ncol]);
        #pragma unroll
        for (int i = 0; i < 8; ++i) {
            const int mrow = m0 + wm * 128 + i * 16 + (lane & 15);
            float4 o;
            o.x = acc[i][j][0] + bv4.x;
            o.y = acc[i][j][1] + bv4.y;
            o.z = acc[i][j][2] + bv4.z;
            o.w = acc[i][j][3] + bv4.w;
            *reinterpret_cast<float4*>(&outB[(size_t)mrow * H + c0 + ncol]) = o;
        }
    }
}

extern "C" void kernel_launch(void* const* d_in, const int* in_sizes, int n_in,
                              void* d_out, int out_size, void* d_ws, size_t ws_size,
                              hipStream_t stream) {
    const float* hs = (const float*)d_in[0];
    const float* wq = (const float*)d_in[1];
    const float* bq = (const float*)d_in[2];
    const float* wk = (const float*)d_in[3];
    const float* bk = (const float*)d_in[4];
    const float* wv = (const float*)d_in[5];
    const float* bv = (const float*)d_in[6];

    unsigned short* A_pk = (unsigned short*)d_ws;                 // 50,331,648 B
    unsigned short* W_pk = A_pk + (size_t)A_TILES * 8192;         //  3,538,944 B
    float* biasb         = (float*)(W_pk + (size_t)W_TILES * 8192);

    hipLaunchKernelGGL(convert_pack, dim3(A_TILES + W_TILES), dim3(256), 0, stream,
                       hs, wq, wk, wv, bq, bk, bv, A_pk, W_pk, biasb);

    hipLaunchKernelGGL(qkv_gemm, dim3(NBLK), dim3(512), 0, stream,
                       A_pk, W_pk, biasb, (float*)d_out);
}

// Round 6
// 220.002 us; speedup vs baseline: 1.0702x; 1.0702x over previous
//
#include <hip/hip_runtime.h>
#include <hip/hip_bf16.h>

// C[32768,2304] = A[32768,768] * W^T + b ; outputs q,k,v [32768,768] fp32 each.
#define M_TOT 32768
#define K_TOT 768
#define N_TOT 2304
#define H     768
#define BM 256
#define BN 256
#define NBN 9                    // N_TOT/BN
#define NBM 128                  // M_TOT/BM
#define NBLK (NBM*NBN)           // 1152, %8==0 -> XCD swizzle bijective
#define NKT  12                  // K-tiles of 64
#define NST  24                  // sub-tiles of BK=32
#define OUT_PER 25165824         // M_TOT*H

typedef __attribute__((ext_vector_type(8))) short bf16x8;
typedef __attribute__((ext_vector_type(8))) unsigned short u16x8;
typedef __attribute__((ext_vector_type(4))) float f32x4;

__device__ __forceinline__ void gld_lds16(const void* g, void* l) {
    __builtin_amdgcn_global_load_lds(
        (const __attribute__((address_space(1))) unsigned int*)g,
        (__attribute__((address_space(3))) unsigned int*)l,
        16, 0, 0);
}

__device__ __forceinline__ unsigned short f2bf_rne(float f) {
    unsigned u = __builtin_bit_cast(unsigned, f);
    unsigned r = (u + 0x7FFFu + ((u >> 16) & 1u)) >> 16;
    return (unsigned short)r;
}

// ---------------------------------------------------------------------------
// Pass 1 (R3-proven, ~25us): fp32 -> bf16 convert + pack into tiled layout
// pk[gran][kt][kb8][row128][8]; granule = 128 rows x 768 k = 98304 elems.
// ---------------------------------------------------------------------------
#define A_TILES 3072             // 256 m-granules x 12 k-tiles
#define W_TILES 216              // 18 row-granules x 12 k-tiles
#define LDSW 68

__global__ void convert_pack(const float* __restrict__ A,
                             const float* __restrict__ wq, const float* __restrict__ wk,
                             const float* __restrict__ wv,
                             const float* __restrict__ bq, const float* __restrict__ bk,
                             const float* __restrict__ bv,
                             unsigned short* __restrict__ A_pk,
                             unsigned short* __restrict__ W_pk,
                             float* __restrict__ biasb) {
    __shared__ float lds_f[128 * LDSW];

    const int tid = threadIdx.x;
    const int t   = blockIdx.x;

    int gt = t * 256 + tid;
    if (gt < 2304) {
        biasb[gt] = (gt < 768) ? bq[gt] : (gt < 1536) ? bk[gt - 768] : bv[gt - 1536];
    }

    const float* src;
    unsigned short* dst;
    if (t < A_TILES) {
        const int mt = t / 12, kt = t - mt * 12;
        src = A + (size_t)mt * 128 * K_TOT + kt * 64;
        dst = A_pk + (size_t)t * 8192;
    } else {
        const int t2 = t - A_TILES;
        const int nt = t2 / 12, kt = t2 - nt * 12;
        const int which = nt / 6;
        const int row0  = (nt - which * 6) * 128;
        const float* w = (which == 0) ? wq : (which == 1) ? wk : wv;
        src = w + (size_t)row0 * K_TOT + kt * 64;
        dst = W_pk + (size_t)t2 * 8192;
    }

    #pragma unroll
    for (int j = 0; j < 8; ++j) {
        int f = j * 256 + tid;
        int row = f >> 4, c4 = f & 15;
        float4 v = *reinterpret_cast<const float4*>(src + (size_t)row * K_TOT + c4 * 4);
        *reinterpret_cast<float4*>(&lds_f[row * LDSW + c4 * 4]) = v;
    }
    __syncthreads();

    #pragma unroll
    for (int j = 0; j < 4; ++j) {
        int c = j * 256 + tid;
        int kb = c >> 7, row = c & 127;
        const float* p = &lds_f[row * LDSW + kb * 8];
        u16x8 o;
        #pragma unroll
        for (int e = 0; e < 8; ++e) o[e] = f2bf_rne(p[e]);
        *reinterpret_cast<u16x8*>(dst + (size_t)c * 8) = o;
    }
}

// ---------------------------------------------------------------------------
// Pass 2: 256x256 bf16 MFMA GEMM — counted-vmcnt sub-tile pipeline, UNPINNED:
//   512 thr = 8 waves (2M x 4N), wave tile 128x64, acc[8][4].
//   Sub-tile = BK=32 (A 16KB + B 16KB, 4 gld_lds/thread). 4-slot ring
//   (128 KiB), 3-sub-tile prefetch lead -> gate s_waitcnt vmcnt(8) +
//   s_barrier (vmcnt BEFORE barrier: each wave proves its own loads landed,
//   barrier makes it collective). NO asm lgkmcnt, NO per-phase sched_barrier
//   (m141 lesson): compiler emits fine-grained lgkmcnt and may overlap
//   phase-1 ds_reads with phase-0 MFMA.
//   Per sub-tile: [gate][reads af0,bf | stageA | bar | 16 MFMA]
//                 [reads af1 | stageB | bar | 16 MFMA].
//   Packed slot [g2][kq4][row128][8]: ds_read_b128 conflict-free (measured 0).
// ---------------------------------------------------------------------------
__global__ __launch_bounds__(512, 1) void qkv_gemm(
        const unsigned short* __restrict__ A_pk,
        const unsigned short* __restrict__ W_pk,
        const float* __restrict__ bias,
        float* __restrict__ out) {

    __shared__ __align__(16) unsigned short sA[4][8192];   // 64 KiB
    __shared__ __align__(16) unsigned short sB[4][8192];   // 64 KiB

    const int tid  = threadIdx.x;
    const int lane = tid & 63;
    const int wid  = tid >> 6;     // 0..7
    const int wm   = wid >> 2;     // 0..1 : rows wm*128..+127
    const int wn   = wid & 3;      // 0..3 : cols wn*64..+63

    int bid = (int)blockIdx.x;
    bid = (bid & 7) * (NBLK / 8) + (bid >> 3);   // XCD-aware (bijective)
    const int bm = bid / NBN;
    const int bn = bid - bm * NBN;
    const int m0 = bm * BM;
    const int n0 = bn * BN;

    // granule bases (granule = 128 rows x 768 k = 98304 elems)
    const unsigned short* aG0 = A_pk + (size_t)(2 * bm) * 98304;
    const unsigned short* aG1 = aG0 + 98304;
    const unsigned short* bG0 = W_pk + (size_t)(2 * bn) * 98304;
    const unsigned short* bG1 = bG0 + 98304;

    // staging: sub-tile u (t=u>>1, kk=u&1): src elem = t*8192 + kk*4096 + tid*8
    // (since tid = kbq*128+row and layout is [kb][row][8]); dst elem = tid*8
    // for granule 0, 4096+tid*8 for granule 1 -> slot layout [g][kq][row][8].
    const int sOff = tid * 8;

    f32x4 acc[8][4];
    #pragma unroll
    for (int i = 0; i < 8; ++i)
        #pragma unroll
        for (int j = 0; j < 4; ++j)
            acc[i][j] = (f32x4){0.f, 0.f, 0.f, 0.f};

    auto stageA = [&](int u) {
        const int sl = u & 3;
        const size_t so = (size_t)(u >> 1) * 8192 + (u & 1) * 4096 + sOff;
        gld_lds16(aG0 + so, &sA[sl][sOff]);
        gld_lds16(aG1 + so, &sA[sl][4096 + sOff]);
    };
    auto stageB = [&](int u) {
        const int sl = u & 3;
        const size_t so = (size_t)(u >> 1) * 8192 + (u & 1) * 4096 + sOff;
        gld_lds16(bG0 + so, &sB[sl][sOff]);
        gld_lds16(bG1 + so, &sB[sl][4096 + sOff]);
    };

    // prologue: FIFO order A(0),B(0),A(1),B(1),A(2),B(2) = 12 loads
    stageA(0); stageB(0);
    stageA(1); stageB(1);
    stageA(2); stageB(2);

    // fragment read byte-offsets within a slot [g][kq][row][8]:
    const int kq  = lane >> 4, l15 = lane & 15;
    const int aOff = wm * 8192 + kq * 2048 + l15 * 16;                  // +mi*256
    const int bOff = (wn >> 1) * 8192 + kq * 2048 + (wn & 1) * 1024 + l15 * 16; // +nj*256

    for (int s = 0; s < NST; ++s) {
        const int sl = s & 3;

        // ---- gate: own sub-tile-s loads landed (vmcnt), then collective (bar)
        if (s <= 21)      { asm volatile("s_waitcnt vmcnt(8)" ::: "memory"); }
        else if (s == 22) { asm volatile("s_waitcnt vmcnt(4)" ::: "memory"); }
        else              { asm volatile("s_waitcnt vmcnt(0)" ::: "memory"); }
        __builtin_amdgcn_s_barrier();
        __builtin_amdgcn_sched_barrier(0);   // only pin: nothing crosses the gate

        const char* pA = (const char*)&sA[sl][0];
        const char* pB = (const char*)&sB[sl][0];

        bf16x8 af0[4], af1[4], bf[4];

        // ---- phase 0: rows wm*128..+63
        #pragma unroll
        for (int i = 0; i < 4; ++i) af0[i] = *(const bf16x8*)(pA + aOff + i * 256);
        #pragma unroll
        for (int j = 0; j < 4; ++j) bf[j]  = *(const bf16x8*)(pB + bOff + j * 256);
        if (s + 3 < NST) stageA(s + 3);
        __builtin_amdgcn_s_barrier();
        __builtin_amdgcn_s_setprio(1);
        #pragma unroll
        for (int i = 0; i < 4; ++i)
            #pragma unroll
            for (int j = 0; j < 4; ++j)
                acc[i][j] = __builtin_amdgcn_mfma_f32_16x16x32_bf16(
                    bf[j], af0[i], acc[i][j], 0, 0, 0);
        __builtin_amdgcn_s_setprio(0);

        // ---- phase 1: rows wm*128+64..+127 (reads may overlap phase-0 MFMA)
        #pragma unroll
        for (int i = 0; i < 4; ++i) af1[i] = *(const bf16x8*)(pA + aOff + (4 + i) * 256);
        if (s + 3 < NST) stageB(s + 3);
        __builtin_amdgcn_s_barrier();
        __builtin_amdgcn_s_setprio(1);
        #pragma unroll
        for (int i = 0; i < 4; ++i)
            #pragma unroll
            for (int j = 0; j < 4; ++j)
                acc[4 + i][j] = __builtin_amdgcn_mfma_f32_16x16x32_bf16(
                    bf[j], af1[i], acc[4 + i][j], 0, 0, 0);
        __builtin_amdgcn_s_setprio(0);
        // next gate barrier closes this sub-tile
    }

    // ---- epilogue: operand-swapped layout -> lane holds 4 consecutive n
    const int which = n0 / H;
    const int c0    = n0 - which * H;
    float* outB = out + (size_t)which * OUT_PER;

    #pragma unroll
    for (int j = 0; j < 4; ++j) {
        const int ncol = wn * 64 + j * 16 + ((lane >> 4) << 2);
        const float4 bv4 = *reinterpret_cast<const float4*>(&bias[n0 + ncol]);
        #pragma unroll
        for (int i = 0; i < 8; ++i) {
            const int mrow = m0 + wm * 128 + i * 16 + (lane & 15);
            float4 o;
            o.x = acc[i][j][0] + bv4.x;
            o.y = acc[i][j][1] + bv4.y;
            o.z = acc[i][j][2] + bv4.z;
            o.w = acc[i][j][3] + bv4.w;
            *reinterpret_cast<float4*>(&outB[(size_t)mrow * H + c0 + ncol]) = o;
        }
    }
}

extern "C" void kernel_launch(void* const* d_in, const int* in_sizes, int n_in,
                              void* d_out, int out_size, void* d_ws, size_t ws_size,
                              hipStream_t stream) {
    const float* hs = (const float*)d_in[0];
    const float* wq = (const float*)d_in[1];
    const float* bq = (const float*)d_in[2];
    const float* wk = (const float*)d_in[3];
    const float* bk = (const float*)d_in[4];
    const float* wv = (const float*)d_in[5];
    const float* bv = (const float*)d_in[6];

    unsigned short* A_pk = (unsigned short*)d_ws;                 // 50,331,648 B
    unsigned short* W_pk = A_pk + (size_t)A_TILES * 8192;         //  3,538,944 B
    float* biasb         = (float*)(W_pk + (size_t)W_TILES * 8192);

    hipLaunchKernelGGL(convert_pack, dim3(A_TILES + W_TILES), dim3(256), 0, stream,
                       hs, wq, wk, wv, bq, bk, bv, A_pk, W_pk, biasb);

    hipLaunchKernelGGL(qkv_gemm, dim3(NBLK), dim3(512), 0, stream,
                       A_pk, W_pk, biasb, (float*)d_out);
}